// Round 4
// baseline (616.175 us; speedup 1.0000x reference)
//
#include <hip/hip_runtime.h>

// Point2DirSum: directional (hor/ver/diag/adiag) length-5 box sums with zero
// padding. in: (N,C,H,W) fp32, out: (N,4C,H,W) fp32, channel-concat order
// [hor, ver, diag, adiag].
//
// R4: write-stream sequentiality. R1 (LDS-phased) and R3 (LDS-free, 24-deep
// MLP) both plateau at ~2.5 TB/s effective while the harness fill hits 78%
// of HBM peak -- the only byte-identical element across all plateaued
// kernels is the store pattern (4 planes 1MB apart, round-robin, 512B
// fragments). Theory: 1MB-strided planes alias DRAM banks; interleaved
// 512B bursts thrash pages. Fix:
//   * stride-2 row ownership (lanes 0-31 even rows, 32-63 odd) -> every
//     store instruction writes 1KB FULLY CONTIGUOUS (two adjacent rows),
//     successive stores extend the run: 4KB contiguous per plane per wave.
//   * plane-major store batching (all hor, then ver, diag, adiag).
// Reads stay streaming: 11 rows x 3 immediate-offset loads per thread.
// FP order per output unchanged (d ascending; hor left-assoc 5-chain).

typedef float f32x4 __attribute__((ext_vector_type(4)));

constexpr int N = 128, C = 16, H = 128, W = 128;
constexpr int TH = 32;               // output rows per block
constexpr int VB = 4;                // output rows per thread (stride 2)

__global__ __launch_bounds__(256, 4)
void Point2DirSum_kernel(const float* __restrict__ in, float* __restrict__ out) {
    const int tid  = threadIdx.x;
    const int wv   = tid >> 6;           // wave 0..3, owns rows [h0+8wv, h0+8wv+8)
    const int lane = tid & 63;
    const int half = lane >> 5;          // 0: even rows, 1: odd rows
    const int l32  = lane & 31;

    constexpr int TILES_PER_IMG = H / TH;            // 4
    const int img = blockIdx.x / TILES_PER_IMG;      // n*C + c
    const int t   = blockIdx.x % TILES_PER_IMG;
    const int h0  = t * TH;

    // Thread computes output rows B, B+2, B+4, B+6 at cols w4..w4+3.
    const int B  = h0 + wv * 8 + half;
    const int w4 = l32 * 4;

    // Input rows needed: B-2 .. B+8 (11 rows), cols w4-2 .. w4+5.
    // Load instr r: half 0 reads row B-2+r, half 1 reads row B-1+r ->
    // adjacent rows, 1KB contiguous per instruction.
    const float* __restrict__ base =
        in + (size_t)img * H * W + (size_t)(B - 2) * W + (w4 - 2);

    const bool c_lo = (w4 != 0);         // cols w4-2,w4-1 valid?
    const bool c_hi = (w4 != W - 4);     // cols w4+4,w4+5 valid?

    float ho[VB][4], ve[VB][4], di[VB][4], ad[VB][4];
    #pragma unroll
    for (int k = 0; k < VB; ++k)
        #pragma unroll
        for (int j = 0; j < 4; ++j) { ve[k][j] = 0.f; di[k][j] = 0.f; ad[k][j] = 0.f; }

    #pragma unroll
    for (int r = 0; r < VB + 7; ++r) {           // input row = B-2+r, r=0..10
        const int gr = B - 2 + r;
        const bool rok = (unsigned)gr < (unsigned)H;  // zero-pad rows
        float e[8];
        #pragma unroll
        for (int kk = 0; kk < 8; ++kk) e[kk] = 0.f;
        if (rok) {
            const float* rp = base + r * W;
            const float4 m = *(const float4*)(rp + 2);   // cols w4..w4+3
            e[2] = m.x; e[3] = m.y; e[4] = m.z; e[5] = m.w;
            if (c_lo) { const float2 lo = *(const float2*)(rp);     e[0] = lo.x; e[1] = lo.y; }
            if (c_hi) { const float2 hi = *(const float2*)(rp + 6); e[6] = hi.x; e[7] = hi.y; }
        }
        // Output k (row B+2k) consumes input row gr at window index d = r-2k.
        //   ver += e[j+2]; diag += e[j+d]; adiag += e[j+4-d];
        //   hor (d==2) = e[j]+e[j+1]+e[j+2]+e[j+3]+e[j+4]  (left-assoc)
        // d ascends with r for each k -> identical FP order to prior kernels.
        #pragma unroll
        for (int k = 0; k < VB; ++k) {
            const int d = r - 2 * k;
            if (d >= 0 && d < 5) {
                #pragma unroll
                for (int j = 0; j < 4; ++j) {
                    ve[k][j] += e[j + 2];
                    di[k][j] += e[j + d];
                    ad[k][j] += e[j + 4 - d];
                }
                if (d == 2) {
                    #pragma unroll
                    for (int j = 0; j < 4; ++j)
                        ho[k][j] = e[j] + e[j + 1] + e[j + 2] + e[j + 3] + e[j + 4];
                }
            }
        }
    }

    const int n = img / C;
    const int c = img - n * C;
    float* __restrict__ outp = out + (((size_t)n * 4 * C + c) * (size_t)H) * W;
    const size_t plane = (size_t)C * H * W;          // stride between dir blocks

    // Plane-major stores: 4 consecutive 1KB-contiguous store instrs per
    // plane (rows B+2k / B+2k+1 across the wave) = 4KB run, then next plane.
    #pragma unroll
    for (int k = 0; k < VB; ++k) {
        const size_t o = (size_t)(B + 2 * k) * W + w4;
        f32x4 v = { ho[k][0], ho[k][1], ho[k][2], ho[k][3] };
        __builtin_nontemporal_store(v, (f32x4*)&outp[o]);
    }
    #pragma unroll
    for (int k = 0; k < VB; ++k) {
        const size_t o = (size_t)(B + 2 * k) * W + w4 + plane;
        f32x4 v = { ve[k][0], ve[k][1], ve[k][2], ve[k][3] };
        __builtin_nontemporal_store(v, (f32x4*)&outp[o]);
    }
    #pragma unroll
    for (int k = 0; k < VB; ++k) {
        const size_t o = (size_t)(B + 2 * k) * W + w4 + 2 * plane;
        f32x4 v = { di[k][0], di[k][1], di[k][2], di[k][3] };
        __builtin_nontemporal_store(v, (f32x4*)&outp[o]);
    }
    #pragma unroll
    for (int k = 0; k < VB; ++k) {
        const size_t o = (size_t)(B + 2 * k) * W + w4 + 3 * plane;
        f32x4 v = { ad[k][0], ad[k][1], ad[k][2], ad[k][3] };
        __builtin_nontemporal_store(v, (f32x4*)&outp[o]);
    }
}

extern "C" void kernel_launch(void* const* d_in, const int* in_sizes, int n_in,
                              void* d_out, int out_size, void* d_ws, size_t ws_size,
                              hipStream_t stream) {
    const float* in = (const float*)d_in[0];
    float* out = (float*)d_out;
    const int grid = N * C * (H / TH);               // 8192 blocks
    Point2DirSum_kernel<<<grid, 256, 0, stream>>>(in, out);
}